// Round 2
// baseline (818.430 us; speedup 1.0000x reference)
//
#include <hip/hip_runtime.h>
#include <math.h>

#define DDIM 16
#define NSTEPS 64
#define BATCH_N 2097152L   // fixed problem size: 2^21 rows (do NOT trust in_sizes units)

typedef _Float16 half4   __attribute__((ext_vector_type(4)));
typedef __fp16   fp16x2  __attribute__((ext_vector_type(2)));  // cvt_pkrtz return type
typedef float    floatx4 __attribute__((ext_vector_type(4)));

// Packed per-lane MFMA A-operand fragments for W^T and (V^T * 1/N), f16.
// 64 steps * 64 lanes * 8 B = 32 KB each. Module-scope device memory:
// no dependence on d_ws / ws_size.
__device__ half4 g_pw[NSTEPS * 64];
__device__ half4 g_pv[NSTEPS * 64];

// ---------------------------------------------------------------------------
// Pre-pack W^T / V^T into per-lane MFMA A-operand fragments (f16).
// For v_mfma_f32_16x16x16_f16, A[m][k]: lane L supplies m = L&15, k = 4*(L>>4)+j.
// We feed A = W_s^T, so lane L, elem j holds W_s^T[L&15][4q+j] = W_s[4q+j][L&15].
// The 1/N residual scale is folded into the V fragments (pure relative scale,
// f16 relative precision unchanged) so the GELU epilogue saves one mul/elem.
// ---------------------------------------------------------------------------
__global__ __launch_bounds__(256) void pack_wv(const float* __restrict__ W,
                                               const float* __restrict__ V)
{
    int t = blockIdx.x * 256 + threadIdx.x;   // 0..4095 = 64 steps * 64 lanes
    int L = t & 63;
    int s = t >> 6;
    int q = L >> 4, r = L & 15;
    const float inv_n = 1.0f / (float)NSTEPS;
    const float* Ws = W + s * DDIM * DDIM;
    const float* Vs = V + s * DDIM * DDIM;
    half4 w, v;
    #pragma unroll
    for (int j = 0; j < 4; ++j) {
        w[j] = (_Float16)Ws[(4 * q + j) * DDIM + r];
        v[j] = (_Float16)(Vs[(4 * q + j) * DDIM + r] * inv_n);
    }
    g_pw[t] = w;
    g_pv[t] = v;
}

// ---------------------------------------------------------------------------
// Main kernel: each wave owns 4 row-tiles (64 rows). State h kept in fp32 in
// the MFMA C/D layout: lane L holds h[row = L&15][cols 4q..4q+3] of its tile.
// Chain (all transposed):  u^T = W^T @ h^T ;  h^T += V'^T @ gelu(u)^T.
// C/D layout == B-operand layout for the transposed chain -> no shuffles/LDS.
// ---------------------------------------------------------------------------
__global__ __launch_bounds__(256) void resnet_mfma_kernel(
    const float* __restrict__ x,
    float* __restrict__ out)
{
    const int tid  = threadIdx.x;
    const int lane = tid & 63;
    const int wave = tid >> 6;
    const int q = lane >> 4, r = lane & 15;

    const long rowbase = (long)blockIdx.x * 256 + (long)wave * 64;

    // Load state: lane reads float4 at (row, 4q) for each of its 4 tiles.
    floatx4 h[4];
    #pragma unroll
    for (int t = 0; t < 4; ++t) {
        const float4* p = reinterpret_cast<const float4*>(
            x + (rowbase + t * 16 + r) * DDIM + 4 * q);
        float4 v = *p;
        h[t][0] = v.x; h[t][1] = v.y; h[t][2] = v.z; h[t][3] = v.w;
    }

    // tanh-GELU as logistic: gelu(x) = x - x/(1 + 2^z), z = K*x*(1 + c1*x^2)
    // with K = 2*0.7978845608*log2(e). Re-associated: z = x * fma(K*c1, x^2, K).
    const float K   = 2.3022082f;
    const float Kc1 = 0.10294340f;   // K * 0.044715

    // Software-prefetch the W/V fragments one step ahead (L1/L2-hot, 64KB total).
    half4 wf = g_pw[lane];
    half4 vf = g_pv[lane];

    for (int s = 0; s < NSTEPS; ++s) {
        int sn = (s < NSTEPS - 1) ? s + 1 : s;
        half4 wfn = g_pw[sn * 64 + lane];
        half4 vfn = g_pv[sn * 64 + lane];

        #pragma unroll
        for (int t = 0; t < 4; ++t) {
            // h (fp32, C/D layout) -> f16 B-operand via packed RTZ converts.
            union { fp16x2 h2[2]; half4 h4; } hb;
            hb.h2[0] = __builtin_amdgcn_cvt_pkrtz(h[t][0], h[t][1]);
            hb.h2[1] = __builtin_amdgcn_cvt_pkrtz(h[t][2], h[t][3]);

            floatx4 zero = {0.f, 0.f, 0.f, 0.f};
            floatx4 u = __builtin_amdgcn_mfma_f32_16x16x16f16(wf, hb.h4, zero, 0, 0, 0);

            // g = GELU(u), elementwise (layout-agnostic); 1/N already in vf.
            float g[4];
            #pragma unroll
            for (int j = 0; j < 4; ++j) {
                float xv = u[j];
                float x2 = xv * xv;
                float z  = xv * fmaf(Kc1, x2, K);
                float e  = __builtin_amdgcn_exp2f(z);
                float rr = __builtin_amdgcn_rcpf(1.0f + e);
                g[j] = fmaf(-xv, rr, xv);          // x * sigmoid(2a); saturates cleanly
            }
            union { fp16x2 h2[2]; half4 h4; } gb;
            gb.h2[0] = __builtin_amdgcn_cvt_pkrtz(g[0], g[1]);
            gb.h2[1] = __builtin_amdgcn_cvt_pkrtz(g[2], g[3]);

            // h += gelu(u) @ (V/N)  (residual add folded into MFMA C operand, fp32)
            h[t] = __builtin_amdgcn_mfma_f32_16x16x16f16(vf, gb.h4, h[t], 0, 0, 0);
        }

        wf = wfn; vf = vfn;
    }

    #pragma unroll
    for (int t = 0; t < 4; ++t) {
        float4 v = make_float4(h[t][0], h[t][1], h[t][2], h[t][3]);
        *reinterpret_cast<float4*>(out + (rowbase + t * 16 + r) * DDIM + 4 * q) = v;
    }
}

extern "C" void kernel_launch(void* const* d_in, const int* in_sizes, int n_in,
                              void* d_out, int out_size, void* d_ws, size_t ws_size,
                              hipStream_t stream) {
    (void)in_sizes; (void)n_in; (void)out_size; (void)d_ws; (void)ws_size;

    const float* x = (const float*)d_in[0];   // [2^21, 16] fp32
    const float* W = (const float*)d_in[1];   // [64, 16, 16] fp32
    const float* V = (const float*)d_in[2];   // [64, 16, 16] fp32
    float* out = (float*)d_out;

    pack_wv<<<16, 256, 0, stream>>>(W, V);

    // Problem size is fixed by the spec; grid hard-coded (bytes-vs-elements
    // ambiguity in in_sizes would 4x the grid -> OOB device fault).
    resnet_mfma_kernel<<<(int)(BATCH_N / 256), 256, 0, stream>>>(x, out);
}

// Round 3
// 756.011 us; speedup vs baseline: 1.0826x; 1.0826x over previous
//
#include <hip/hip_runtime.h>
#include <math.h>

#define DDIM 16
#define NSTEPS 64
#define BATCH_N 2097152L   // fixed problem size: 2^21 rows (do NOT trust in_sizes units)

typedef _Float16 half4   __attribute__((ext_vector_type(4)));
typedef __fp16   fp16x2  __attribute__((ext_vector_type(2)));  // cvt_pkrtz return type
typedef float    floatx4 __attribute__((ext_vector_type(4)));

// Packed per-lane MFMA A-operand fragments for W^T and (V^T * 1/N), f16.
// 64 steps * 64 lanes * 8 B = 32 KB each. Module-scope device memory.
__device__ half4 g_pw[NSTEPS * 64];
__device__ half4 g_pv[NSTEPS * 64];

// ---------------------------------------------------------------------------
// Pre-pack W^T / V^T into per-lane MFMA A-operand fragments (f16).
// For v_mfma_f32_16x16x16_f16, A[m][k]: lane L supplies m = L&15, k = 4*(L>>4)+j.
// We feed A = W_s^T, so lane L, elem j holds W_s^T[L&15][4q+j] = W_s[4q+j][L&15].
// 1/N residual scale folded into V fragments.
// ---------------------------------------------------------------------------
__global__ __launch_bounds__(256) void pack_wv(const float* __restrict__ W,
                                               const float* __restrict__ V)
{
    int t = blockIdx.x * 256 + threadIdx.x;   // 0..4095 = 64 steps * 64 lanes
    int L = t & 63;
    int s = t >> 6;
    int q = L >> 4, r = L & 15;
    const float inv_n = 1.0f / (float)NSTEPS;
    const float* Ws = W + s * DDIM * DDIM;
    const float* Vs = V + s * DDIM * DDIM;
    half4 w, v;
    #pragma unroll
    for (int j = 0; j < 4; ++j) {
        w[j] = (_Float16)Ws[(4 * q + j) * DDIM + r];
        v[j] = (_Float16)(Vs[(4 * q + j) * DDIM + r] * inv_n);
    }
    g_pw[t] = w;
    g_pv[t] = v;
}

// ---------------------------------------------------------------------------
// Main kernel: each wave owns 4 row-tiles (64 rows). State h kept in fp32 in
// the MFMA C/D layout. Chain: u^T = W^T @ h^T ; h^T += V'^T @ gelu(u)^T.
//
// Phase-split step body (this round's change): all 4 tiles' h->f16 cvts, then
// all 4 first MFMAs, then all 4 GELUs, then all 4 accumulate-MFMAs. Combined
// with __launch_bounds__(256,6) (VGPR cap ~85 instead of the 32 the compiler
// chose when targeting pointless 16-wave occupancy), this lets the scheduler
// keep 4 independent chains in flight per wave and hide exp2/rcp/MFMA latency.
// Occupancy 6/8 waves per SIMD -- HW caps at 8 anyway; measured occupancy was 84%.
// ---------------------------------------------------------------------------
__global__ __launch_bounds__(256, 6) void resnet_mfma_kernel(
    const float* __restrict__ x,
    float* __restrict__ out)
{
    const int tid  = threadIdx.x;
    const int lane = tid & 63;
    const int wave = tid >> 6;
    const int q = lane >> 4, r = lane & 15;

    const long rowbase = (long)blockIdx.x * 256 + (long)wave * 64;

    // Load state: lane reads float4 at (row, 4q) for each of its 4 tiles.
    floatx4 h[4];
    #pragma unroll
    for (int t = 0; t < 4; ++t) {
        const float4* p = reinterpret_cast<const float4*>(
            x + (rowbase + t * 16 + r) * DDIM + 4 * q);
        float4 v = *p;
        h[t][0] = v.x; h[t][1] = v.y; h[t][2] = v.z; h[t][3] = v.w;
    }

    // tanh-GELU as logistic: gelu(x) = x - x/(1 + 2^z), z = x * fma(K*c1, x^2, K)
    const float K   = 2.3022082f;
    const float Kc1 = 0.10294340f;   // K * 0.044715

    // Software-prefetch the W/V fragments one step ahead (L1/L2-hot, 64KB total).
    half4 wf = g_pw[lane];
    half4 vf = g_pv[lane];

    for (int s = 0; s < NSTEPS; ++s) {
        int sn = (s < NSTEPS - 1) ? s + 1 : s;
        half4 wfn = g_pw[sn * 64 + lane];
        half4 vfn = g_pv[sn * 64 + lane];

        // Phase 1: h (fp32, C/D layout) -> f16 B-operand, all tiles.
        union { fp16x2 h2[2]; half4 h4; } hb[4];
        #pragma unroll
        for (int t = 0; t < 4; ++t) {
            hb[t].h2[0] = __builtin_amdgcn_cvt_pkrtz(h[t][0], h[t][1]);
            hb[t].h2[1] = __builtin_amdgcn_cvt_pkrtz(h[t][2], h[t][3]);
        }

        // Phase 2: u = W^T @ h^T, all tiles (4 independent MFMAs).
        floatx4 u[4];
        #pragma unroll
        for (int t = 0; t < 4; ++t) {
            floatx4 zero = {0.f, 0.f, 0.f, 0.f};
            u[t] = __builtin_amdgcn_mfma_f32_16x16x16f16(wf, hb[t].h4, zero, 0, 0, 0);
        }

        // Phase 3: g = GELU(u) -> f16, all tiles (16 independent element chains).
        union { fp16x2 h2[2]; half4 h4; } gb[4];
        #pragma unroll
        for (int t = 0; t < 4; ++t) {
            float g[4];
            #pragma unroll
            for (int j = 0; j < 4; ++j) {
                float xv = u[t][j];
                float x2 = xv * xv;
                float z  = xv * fmaf(Kc1, x2, K);
                float e  = __builtin_amdgcn_exp2f(z);
                float rr = __builtin_amdgcn_rcpf(1.0f + e);
                g[j] = fmaf(-xv, rr, xv);          // x * sigmoid(2a)
            }
            gb[t].h2[0] = __builtin_amdgcn_cvt_pkrtz(g[0], g[1]);
            gb[t].h2[1] = __builtin_amdgcn_cvt_pkrtz(g[2], g[3]);
        }

        // Phase 4: h += gelu(u) @ (V/N), all tiles (residual in MFMA C operand).
        #pragma unroll
        for (int t = 0; t < 4; ++t) {
            h[t] = __builtin_amdgcn_mfma_f32_16x16x16f16(vf, gb[t].h4, h[t], 0, 0, 0);
        }

        wf = wfn; vf = vfn;
    }

    #pragma unroll
    for (int t = 0; t < 4; ++t) {
        float4 v = make_float4(h[t][0], h[t][1], h[t][2], h[t][3]);
        *reinterpret_cast<float4*>(out + (rowbase + t * 16 + r) * DDIM + 4 * q) = v;
    }
}

extern "C" void kernel_launch(void* const* d_in, const int* in_sizes, int n_in,
                              void* d_out, int out_size, void* d_ws, size_t ws_size,
                              hipStream_t stream) {
    (void)in_sizes; (void)n_in; (void)out_size; (void)d_ws; (void)ws_size;

    const float* x = (const float*)d_in[0];   // [2^21, 16] fp32
    const float* W = (const float*)d_in[1];   // [64, 16, 16] fp32
    const float* V = (const float*)d_in[2];   // [64, 16, 16] fp32
    float* out = (float*)d_out;

    pack_wv<<<16, 256, 0, stream>>>(W, V);

    // Problem size fixed by spec; grid hard-coded.
    resnet_mfma_kernel<<<(int)(BATCH_N / 256), 256, 0, stream>>>(x, out);
}